// Round 5
// baseline (343.226 us; speedup 1.0000x reference)
//
#include <hip/hip_runtime.h>
#include <cstdint>
#include <math.h>

#define B_ 64
#define S_ 512
#define H_ 1024
#define T_ 24
#define TP_ 32     // W padded to 32 rows (zeros) so B-fragment loads never go OOB
#define NC_ 32     // chunks per batch (parallel-scan)
#define CL_ 16     // chunk length in steps
#define KST_ 1040  // floats per (batch,chunk) record: 32x32 K row-major + Ls + pad

typedef unsigned int u32;
typedef unsigned short u16;
typedef __attribute__((ext_vector_type(8))) short short8v;  // 8 bf16 = 4 VGPRs
typedef __attribute__((ext_vector_type(4))) float f32x4;
typedef __attribute__((ext_vector_type(4))) u32 uint4v;

// readlane: value from lane `sl` (wave-uniform index ok), bitcast through uint
__device__ __forceinline__ float rl_f32(float x, int sl) {
    return __uint_as_float(__builtin_amdgcn_readlane(__float_as_uint(x), sl));
}

// Exact-ish two-term split: f = hi + lo (both bf16 by truncation).
// Packs two elements' hi (lo) into one u32, low element in low half.
__device__ __forceinline__ void split_pk(float f0, float f1, u32& hpk, u32& lpk) {
    const u32 u0 = __float_as_uint(f0), u1 = __float_as_uint(f1);
    const u32 t1 = u1 & 0xffff0000u;
    hpk = (u0 >> 16) | t1;
    const float fl0 = f0 - __uint_as_float(u0 & 0xffff0000u);
    const float fl1 = f1 - __uint_as_float(t1);
    lpk = (__float_as_uint(fl0) >> 16) | (__float_as_uint(fl1) & 0xffff0000u);
}

// ---------------------------------------------------------------------------
// Kernel 0: one-shot W split fp32 -> bf16 hi/lo (RTNE), padded to 32 rows.
// Also zeroes the loss accumulator out[0] and the per-batch completion
// counters (both re-zeroed every graph replay; workspace is poisoned).
// ---------------------------------------------------------------------------
__global__ __launch_bounds__(256) void wcvt_kernel(const float* __restrict__ W,
                                                   u16* __restrict__ Wh,
                                                   u16* __restrict__ Wl,
                                                   float* __restrict__ out,
                                                   int* __restrict__ cnt) {
    const int i = blockIdx.x * 256 + threadIdx.x;       // 0 .. 32*1024-1
    if (i == 0) out[0] = 0.f;
    if (i < B_) cnt[i] = 0;
    const int t = i >> 10;
    const float f = (t < T_) ? W[i] : 0.f;              // W is [24][1024]; i = t*1024+k
    const u32 u = __float_as_uint(f);
    const u32 rh = u + 0x7fffu + ((u >> 16) & 1u);      // RTNE
    const u16 hb = (u16)(rh >> 16);
    const float fh = __uint_as_float((u32)hb << 16);
    const float fl = f - fh;
    const u32 u2 = __float_as_uint(fl);
    const u32 rl2 = u2 + 0x7fffu + ((u2 >> 16) & 1u);
    Wh[i] = hb;
    Wl[i] = (u16)(rl2 >> 16);
}

// ---------------------------------------------------------------------------
// FUSED kernel: block (b,c) = one wave.
//  Phase 1 (gemm): emission rows 16c..16c+15 via MFMA bf16 hi/lo split
//    (verified conventions, by prior rounds passing:
//     A[m][k]: m=lane&15, k=(lane>>4)*8+e ; B[k][n]: n=lane&15, k=(lane>>4)*8+e
//     D[m][n]: n=lane&15, m=(lane>>4)*4+reg).
//    Written to global emission (an output) AND a 16x32 LDS tile (cols 24..31
//    are exactly 0: zero-padded W rows + zero bias).
//  Phase 2 (chunk): 16 forward steps s=16c..16c+15 (s=0 skipped), operator
//    K <- diagX_s * (E^T * K), K init I(32), X from the LDS emission tile.
//    D->B row regrouping via LDS bounce; exact power-of-2 renorms.
//  Phase 3: store K + log-scale; last block of each batch (device-scope
//    counter, threadfence pattern) computes logZ + gold score + loss.
// Chunk boundary shift vs R3/R4 ([16c,16c+16) instead of [1+16c,...)) changes
// only the factorization; the ordered product over s=1..511 is identical.
// ---------------------------------------------------------------------------
#define FINE_DECL(i) const float E##i##_ = 0.f; (void)E##i##_;

__global__ __launch_bounds__(64, 1) void fused_kernel(const float* __restrict__ feats,
                                                      const u16* __restrict__ Wh,
                                                      const u16* __restrict__ Wl,
                                                      const float* __restrict__ bias,
                                                      const float* __restrict__ trans,
                                                      const int* __restrict__ target,
                                                      const int* __restrict__ mask,
                                                      float* __restrict__ emission,
                                                      float* __restrict__ wsK,
                                                      int* __restrict__ cnt,
                                                      float* __restrict__ out) {
    __shared__ float em_lds[16][32];    // this block's emission rows (cols 24..31 == 0)
    __shared__ u32 lds[2][2][16][18];   // bounce: [hl][J][rowpair][col(16)+pad]

    const int bid = blockIdx.x;
    const int c_ = bid & (NC_ - 1);     // chunk
    const int b  = bid >> 5;
    const int l  = threadIdx.x;
    const int cc = l & 15;              // col-in-tile (and A-row in phase 1)
    const int q  = l >> 4;              // lane quarter (k-group in phase 1)
    const int aq4 = (l & 48);           // 4*(4q) bytes, bpermute base

    const float* em = emission + (long)b * S_ * T_;
    const int* mk = mask + b * S_;

    // ---------------- Phase 1: emission GEMM for rows 16c..16c+15 ----------
    {
        const long row0 = (long)b * S_ + 16 * c_;
        const float* ap  = feats + (row0 + cc) * H_ + q * 8;
        const u16* bh0p = Wh + cc * H_ + q * 8;           // cols 0..15
        const u16* bl0p = Wl + cc * H_ + q * 8;
        const u16* bh1p = Wh + (cc + 16) * H_ + q * 8;    // cols 16..31 (zero-padded)
        const u16* bl1p = Wl + (cc + 16) * H_ + q * 8;

        f32x4 acc0 = {0.f, 0.f, 0.f, 0.f};
        f32x4 acc1 = {0.f, 0.f, 0.f, 0.f};

#pragma unroll 4
        for (int kk = 0; kk < H_ / 32; ++kk) {
            const int ko = kk * 32;
            const float4 a0 = *(const float4*)(ap + ko);
            const float4 a1 = *(const float4*)(ap + ko + 4);
            const short8v bh0 = *(const short8v*)(bh0p + ko);
            const short8v bl0 = *(const short8v*)(bl0p + ko);
            const short8v bh1 = *(const short8v*)(bh1p + ko);
            const short8v bl1 = *(const short8v*)(bl1p + ko);

            u32 h0, l0, h1, l1, h2, l2, h3, l3;
            split_pk(a0.x, a0.y, h0, l0);
            split_pk(a0.z, a0.w, h1, l1);
            split_pk(a1.x, a1.y, h2, l2);
            split_pk(a1.z, a1.w, h3, l3);
            const uint4v hv = {h0, h1, h2, h3};
            const uint4v lv = {l0, l1, l2, l3};
            const short8v ah = __builtin_bit_cast(short8v, hv);
            const short8v al = __builtin_bit_cast(short8v, lv);

            acc0 = __builtin_amdgcn_mfma_f32_16x16x32_bf16(al, bh0, acc0, 0, 0, 0);
            acc0 = __builtin_amdgcn_mfma_f32_16x16x32_bf16(ah, bl0, acc0, 0, 0, 0);
            acc0 = __builtin_amdgcn_mfma_f32_16x16x32_bf16(ah, bh0, acc0, 0, 0, 0);
            acc1 = __builtin_amdgcn_mfma_f32_16x16x32_bf16(al, bh1, acc1, 0, 0, 0);
            acc1 = __builtin_amdgcn_mfma_f32_16x16x32_bf16(ah, bl1, acc1, 0, 0, 0);
            acc1 = __builtin_amdgcn_mfma_f32_16x16x32_bf16(ah, bh1, acc1, 0, 0, 0);
        }

        // epilogue: D row = 4q+r, col = cc (acc0) / 16+cc (acc1)
        const float b0 = bias[cc];
        const float b1 = (cc + 16 < T_) ? bias[cc + 16] : 0.f;
#pragma unroll
        for (int r = 0; r < 4; ++r) {
            const float e0 = acc0[r] + b0;
            const float e1 = acc1[r] + b1;     // == 0 exactly for cols >= 24
            em_lds[4 * q + r][cc] = e0;
            em_lds[4 * q + r][16 + cc] = e1;
            float* op = emission + (row0 + 4 * q + r) * T_;
            op[cc] = e0;
            if (cc + 16 < T_) op[16 + cc] = e1;
        }
    }
    // single wave: DS-pipe in-order + compiler lgkmcnt — no barrier needed

    // ---------------- Phase 2: chunk operator over steps 16c..16c+15 -------
    // len = sum(mask row) (prefix-contiguous by construction)
    int mc = 0;
#pragma unroll
    for (int k = 0; k < 8; ++k) mc += mk[l + k * 64];
#pragma unroll
    for (int off = 32; off; off >>= 1) mc += __shfl_xor(mc, off);
    const int len = __builtin_amdgcn_readfirstlane(mc);

    const int s0_ = 16 * c_;
    const int send = min(s0_ + CL_, len);   // uniform

    // A-frags: A_I[m][k] = E^T[16I+cc][8q+e] = exp(trans[(8q+e)*24 + 16I+cc])
    short8v Ah[2], Al[2];
#pragma unroll
    for (int I = 0; I < 2; ++I) {
        const int j = 16 * I + cc;
        u32 hw[4], lw[4];
#pragma unroll
        for (int w = 0; w < 4; ++w) {
            const int t0 = 8 * q + 2 * w;
            const float v0 = (t0 < 24 && j < 24) ? __expf(trans[t0 * T_ + j]) : 0.f;
            const float v1 = (t0 + 1 < 24 && j < 24) ? __expf(trans[(t0 + 1) * T_ + j]) : 0.f;
            split_pk(v0, v1, hw[w], lw[w]);
        }
        const uint4v hv = {hw[0], hw[1], hw[2], hw[3]};
        const uint4v lv = {lw[0], lw[1], lw[2], lw[3]};
        Ah[I] = __builtin_bit_cast(short8v, hv);
        Al[I] = __builtin_bit_cast(short8v, lv);
    }

    // K regs (C/D layout): K[I][J] reg r holds K[16I+4q+r][16J+cc]; init identity
    f32x4 K[2][2];
#pragma unroll
    for (int I = 0; I < 2; ++I)
#pragma unroll
        for (int J = 0; J < 2; ++J)
#pragma unroll
            for (int r = 0; r < 4; ++r)
                K[I][J][r] = (16 * I + 4 * q + r == 16 * J + cc) ? 1.f : 0.f;

    // initial B words (identity): word w covers k = 8q+2w, 8q+2w+1; col 16J+cc
    u32 bh[2][4], bl[2][4];
#pragma unroll
    for (int J = 0; J < 2; ++J)
#pragma unroll
        for (int w = 0; w < 4; ++w) {
            const int k0 = 8 * q + 2 * w, col = 16 * J + cc;
            bh[J][w] = (k0 == col ? 0x3f80u : 0u) | (k0 + 1 == col ? 0x3f800000u : 0u);
            bl[J][w] = 0u;
        }

    float Ls = 0.f;
    const f32x4 z4 = {0.f, 0.f, 0.f, 0.f};

#pragma unroll
    for (int k = 0; k < CL_; ++k) {
        const int s = s0_ + k;
        if (s > 0 && s < send) {        // uniform branch (skips s=0 in chunk 0)
            const uint4v bh0v = {bh[0][0], bh[0][1], bh[0][2], bh[0][3]};
            const uint4v bh1v = {bh[1][0], bh[1][1], bh[1][2], bh[1][3]};
            const uint4v bl0v = {bl[0][0], bl[0][1], bl[0][2], bl[0][3]};
            const uint4v bl1v = {bl[1][0], bl[1][1], bl[1][2], bl[1][3]};
            const short8v B0h = __builtin_bit_cast(short8v, bh0v);
            const short8v B1h = __builtin_bit_cast(short8v, bh1v);
            const short8v B0l = __builtin_bit_cast(short8v, bl0v);
            const short8v B1l = __builtin_bit_cast(short8v, bl1v);

            f32x4 acc[2][2];
#pragma unroll
            for (int I = 0; I < 2; ++I) {
                acc[I][0] = __builtin_amdgcn_mfma_f32_16x16x32_bf16(Ah[I], B0h, z4, 0, 0, 0);
                acc[I][0] = __builtin_amdgcn_mfma_f32_16x16x32_bf16(Ah[I], B0l, acc[I][0], 0, 0, 0);
                acc[I][0] = __builtin_amdgcn_mfma_f32_16x16x32_bf16(Al[I], B0h, acc[I][0], 0, 0, 0);
                acc[I][1] = __builtin_amdgcn_mfma_f32_16x16x32_bf16(Ah[I], B1h, z4, 0, 0, 0);
                acc[I][1] = __builtin_amdgcn_mfma_f32_16x16x32_bf16(Ah[I], B1l, acc[I][1], 0, 0, 0);
                acc[I][1] = __builtin_amdgcn_mfma_f32_16x16x32_bf16(Al[I], B1h, acc[I][1], 0, 0, 0);
            }

            // row scales X[row] from the local emission tile (row k of this block)
            const float X = __expf(em_lds[k][l & 31]);   // lanes 24..31: exp(0)=1, rows are 0 anyway
            const int xi = __float_as_int(X);
            float xr0[4], xr1[4];
#pragma unroll
            for (int r = 0; r < 4; ++r) {
                xr0[r] = __int_as_float(__builtin_amdgcn_ds_bpermute(aq4 + 4 * r, xi));
                xr1[r] = __int_as_float(__builtin_amdgcn_ds_bpermute(aq4 + 64 + 4 * r, xi));
            }
#pragma unroll
            for (int J = 0; J < 2; ++J)
#pragma unroll
                for (int r = 0; r < 4; ++r) {
                    K[0][J][r] = acc[0][J][r] * xr0[r];
                    K[1][J][r] = acc[1][J][r] * xr1[r];
                }

            if (k == 7 || k == CL_ - 1) {   // exact power-of-2 renorm
                float mx = K[0][0][0];
#pragma unroll
                for (int I = 0; I < 2; ++I)
#pragma unroll
                    for (int J = 0; J < 2; ++J)
#pragma unroll
                        for (int r = 0; r < 4; ++r) mx = fmaxf(mx, K[I][J][r]);
#pragma unroll
                for (int off = 32; off; off >>= 1) mx = fmaxf(mx, __shfl_xor(mx, off));
                const u32 ef = __float_as_uint(mx) & 0x7f800000u;
                const float inv = __uint_as_float(0x7f000000u - ef);
#pragma unroll
                for (int I = 0; I < 2; ++I)
#pragma unroll
                    for (int J = 0; J < 2; ++J)
#pragma unroll
                        for (int r = 0; r < 4; ++r) K[I][J][r] *= inv;
                Ls += (float)((int)(ef >> 23) - 127) * 0.6931471805599453f;
            }

            if (k < CL_ - 1) {
                // pack K to bf16 hi/lo pairs and bounce through LDS to B layout
#pragma unroll
                for (int I = 0; I < 2; ++I)
#pragma unroll
                    for (int J = 0; J < 2; ++J)
#pragma unroll
                        for (int m = 0; m < 2; ++m) {
                            u32 h, lo_w;
                            split_pk(K[I][J][2 * m], K[I][J][2 * m + 1], h, lo_w);
                            const int p = 8 * I + 2 * q + m;
                            lds[0][J][p][cc] = h;
                            lds[1][J][p][cc] = lo_w;
                        }
#pragma unroll
                for (int J = 0; J < 2; ++J)
#pragma unroll
                    for (int w = 0; w < 4; ++w) {
                        bh[J][w] = lds[0][J][4 * q + w][cc];
                        bl[J][w] = lds[1][J][4 * q + w][cc];
                    }
            }
        }
    }

    // ---------------- Phase 3: publish K, last block finalizes -------------
    float* outp = wsK + (long)(b * NC_ + c_) * KST_;
#pragma unroll
    for (int I = 0; I < 2; ++I)
#pragma unroll
        for (int J = 0; J < 2; ++J)
#pragma unroll
            for (int r = 0; r < 4; ++r)
                outp[(16 * I + 4 * q + r) * 32 + 16 * J + cc] = K[I][J][r];
    if (l == 0) outp[1024] = Ls;

    __threadfence();                    // make K/Ls/emission visible device-wide
    int myprev = 0;
    if (l == 0) myprev = atomicAdd(cnt + b, 1);
    myprev = __shfl(myprev, 0);
    if (myprev != NC_ - 1) return;
    __threadfence();                    // acquire side

    // ---- finalize for batch b (this is the 32nd/last chunk block) ----
    const int j = l;
    const int jj = j < 24 ? j : 23;
    float p = (j < 24) ? __expf(em[j]) : 0.f;   // p0
    float C = 0.f;

    for (int c = 0; c < NC_; ++c) {
        const float* base = wsK + (long)(b * NC_ + c) * KST_;
        C += base[1024];                        // chunk log-scale (uniform)
        const float4* rp = (const float4*)(base + jj * 32);
        const float4 k0 = rp[0], k1 = rp[1], k2 = rp[2], k3 = rp[3], k4 = rp[4], k5 = rp[5];
        float s0 = 0.f, s1 = 0.f, s2 = 0.f, s3 = 0.f;
#define ACC4(kv, t0)                                                           \
        s0 = fmaf(rl_f32(p, (t0) + 0), kv.x, s0);                              \
        s1 = fmaf(rl_f32(p, (t0) + 1), kv.y, s1);                              \
        s2 = fmaf(rl_f32(p, (t0) + 2), kv.z, s2);                              \
        s3 = fmaf(rl_f32(p, (t0) + 3), kv.w, s3);
        ACC4(k0, 0) ACC4(k1, 4) ACC4(k2, 8) ACC4(k3, 12) ACC4(k4, 16) ACC4(k5, 20)
#undef ACC4
        p = (j < 24) ? ((s0 + s1) + (s2 + s3)) : 0.f;
        // exact power-of-2 renorm by wave max
        float mx = p;
#pragma unroll
        for (int off = 32; off; off >>= 1) mx = fmaxf(mx, __shfl_xor(mx, off));
        const u32 ef = __float_as_uint(mx) & 0x7f800000u;
        p *= __uint_as_float(0x7f000000u - ef);
        C += (float)((int)(ef >> 23) - 127) * 0.6931471805599453f;
    }

    float ex = p;                               // lanes>=24 already 0
#pragma unroll
    for (int off = 32; off; off >>= 1) ex += __shfl_down(ex, off);

    // gold-path score (all 64 lanes)
    float ssum = 0.f;
#pragma unroll
    for (int kk = 0; kk < S_ / 64; ++kk) {
        const int s = j + kk * 64;
        if (mk[s]) {
            const int tg = target[b * S_ + s];
            float v = em[s * T_ + tg];
            if (s > 0) v += trans[target[b * S_ + s - 1] * T_ + tg];
            ssum += v;
        }
    }
#pragma unroll
    for (int off = 32; off; off >>= 1) ssum += __shfl_down(ssum, off);

    if (j == 0) {
        const float logZ = C + __logf(ex);
        atomicAdd(out, (logZ - ssum) * (1.0f / B_));
    }
}

extern "C" void kernel_launch(void* const* d_in, const int* in_sizes, int n_in,
                              void* d_out, int out_size, void* d_ws, size_t ws_size,
                              hipStream_t stream) {
    const float* feats  = (const float*)d_in[0];
    const int*   target = (const int*)d_in[1];
    const int*   mask   = (const int*)d_in[2];
    const float* W      = (const float*)d_in[3];
    const float* bias   = (const float*)d_in[4];
    const float* trans  = (const float*)d_in[5];

    float* out = (float*)d_out;
    float* emission = out + 1;            // output 1, written in place
    u16* Wh = (u16*)d_ws;                 // 32*1024 bf16 = 64 KB
    u16* Wl = Wh + TP_ * H_;              // 64 KB
    float* wsK = (float*)((char*)d_ws + 131072);      // 2048 * 1040 floats ~ 8.5 MB
    int* cnt = (int*)((char*)d_ws + 131072 + (size_t)B_ * NC_ * KST_ * 4);

    wcvt_kernel<<<(TP_ * H_) / 256, 256, 0, stream>>>(W, Wh, Wl, out, cnt);
    fused_kernel<<<B_ * NC_, 64, 0, stream>>>(feats, Wh, Wl, bias, trans, target, mask,
                                              emission, wsK, cnt, out);
}